// Round 1
// baseline (181.691 us; speedup 1.0000x reference)
//
#include <hip/hip_runtime.h>
#include <cstdint>
#include <cstddef>

typedef unsigned int u32;
typedef unsigned long long u64;

#define NTOT 122740      // total proposals per batch
#define NQ   30685       // NTOT/4 uint4 per batch
#define NPAIR 61370      // NTOT/2 proposal pairs per batch
#define KTOP 1024        // sorted top-K per batch (expected NMS scan depth ~115)
#define WIN  256         // IoU-matrix window over the sorted list
#define NBIN 4096
#define SCORE_T 0.25f
#define TBITS 0x3E800000u   // bit pattern of 0.25f
#define CSTRIDE 64          // counter padding (u32s) -> 256 B apart

// level layout: [offset, count) per pyramid level (batch strides in floats: N*6)
// L2: [0,      92416)  152x152 s4   N=92416
// L3: [92416,  115520) 76x76   s8   N=23104
// L4: [115520, 121296) 38x38   s16  N=5776
// L5: [121296, 122740) 19x19   s32  N=1444

// ws layout (bytes):
//   hist:     32*4096*4 = 524288   @ 0
//   counters: 32*64*4   = 8192     @ 524288
//   compact:  32*1024*8 = 262144   @ 532480
//   scores:   32*NTOT*4 = 15710720 @ 794624
#define WS_COUNTERS 524288
#define WS_COMPACT  532480
#define WS_SCORES   794624

// ---------------------------------------------------------------- helpers
__device__ __forceinline__ float sigm(float x) { return 1.0f / (1.0f + expf(-x)); }

// valid scores [0.25,1) -> bins 1..4095 (monotone in bits); 0 = invalid
__device__ __forceinline__ int score_bin(u32 bits) {
  return min(4095, 1 + (int)((bits - TBITS) >> 12));
}

__device__ __forceinline__ u64 shfl_xor_u64(u64 x, int m) {
  int lo = __shfl_xor((int)(u32)x, m, 64);
  int hi = __shfl_xor((int)(u32)(x >> 32), m, 64);
  return ((u64)(u32)hi << 32) | (u32)lo;
}

__device__ float4 decode_box_from_gidx(u32 gidx, int b,
    const float* __restrict__ p2, const float* __restrict__ p3,
    const float* __restrict__ p4, const float* __restrict__ p5)
{
  const float* p; int t, H, W; float stride;
  float aw0, ah0, aw1, ah1, aw2, ah2, aw3, ah3;
  if (gidx < 92416u) {
    p = p2 + (size_t)b * 92416 * 6; t = (int)gidx; H = 152; W = 152; stride = 4.0f;
    aw0=12.f; ah0=16.f; aw1=19.f; ah1=36.f; aw2=40.f; ah2=28.f; aw3=36.f; ah3=75.f;
  } else if (gidx < 115520u) {
    p = p3 + (size_t)b * 23104 * 6; t = (int)(gidx - 92416u); H = 76; W = 76; stride = 8.0f;
    aw0=36.f; ah0=75.f; aw1=76.f; ah1=55.f; aw2=72.f; ah2=146.f; aw3=142.f; ah3=110.f;
  } else if (gidx < 121296u) {
    p = p4 + (size_t)b * 5776 * 6; t = (int)(gidx - 115520u); H = 38; W = 38; stride = 16.0f;
    aw0=72.f; ah0=146.f; aw1=142.f; ah1=110.f; aw2=192.f; ah2=243.f; aw3=459.f; ah3=401.f;
  } else {
    p = p5 + (size_t)b * 1444 * 6; t = (int)(gidx - 121296u); H = 19; W = 19; stride = 32.0f;
    aw0=142.f; ah0=110.f; aw1=192.f; ah1=243.f; aw2=300.f; ah2=300.f; aw3=459.f; ah3=401.f;
  }
  int HW = H * W;
  int a = t / HW;
  int r = t - a * HW;
  int y = r / W;
  int x = r - y * W;
  const float* q = p + (size_t)t * 6;
  float2 t01 = *(const float2*)(q + 0);
  float2 t23 = *(const float2*)(q + 2);
  float cx = (sigm(t01.x) + (float)x) * stride;
  float cy = (sigm(t01.y) + (float)y) * stride;
  float aw = (a == 0) ? aw0 : (a == 1) ? aw1 : (a == 2) ? aw2 : aw3;
  float ah = (a == 0) ? ah0 : (a == 1) ? ah1 : (a == 2) ? ah2 : ah3;
  float bw = expf(t23.x) * aw;
  float bh = expf(t23.y) * ah;
  return make_float4(cx - 0.5f * bw, cy - 0.5f * bh, cx + 0.5f * bw, cy + 0.5f * bh);
}

__device__ __forceinline__ bool iou_gt(float4 A, float4 B) {
  float ltx = fmaxf(A.x, B.x), lty = fmaxf(A.y, B.y);
  float rbx = fminf(A.z, B.z), rby = fminf(A.w, B.w);
  float w = fmaxf(rbx - ltx, 0.0f), h = fmaxf(rby - lty, 0.0f);
  float inter = w * h;
  float a1 = fmaxf(A.z - A.x, 0.0f) * fmaxf(A.w - A.y, 0.0f);
  float a2 = fmaxf(B.z - B.x, 0.0f) * fmaxf(B.w - B.y, 0.0f);
  float iou = inter / (a1 + a2 - inter + 1e-9f);
  return iou > 0.5f;
}

// ---------------------------------------------------------------- Z: zero hist+counters
__global__ __launch_bounds__(1024)
void zero_kernel(u32* w) {
  int t = blockIdx.x * 1024 + threadIdx.x;   // 130*1024 = 133120 u32 = hist+counters
  if (t < 133120) w[t] = 0u;
}

// ---------------------------------------------------------------- A: decode scores + hist
// Each block: 2048 proposal pairs. Loads ONLY the two float4s per pair containing
// conf/cls (skips box-regression words). Block-local LDS histogram, atomic flush.
__global__ __launch_bounds__(256)
void decode_score_hist(const float* __restrict__ p2, const float* __restrict__ p3,
                       const float* __restrict__ p4, const float* __restrict__ p5,
                       u32* __restrict__ scores, u32* __restrict__ hist)
{
  __shared__ u32 lhist[NBIN];
  const int tid = threadIdx.x;
  const int b = blockIdx.y;
  for (int i = tid; i < NBIN; i += 256) lhist[i] = 0u;
  __syncthreads();

  uint2* srow = (uint2*)(scores + (size_t)b * NTOT);
  const int pbase = blockIdx.x * 2048;
  #pragma unroll 2
  for (int k = 0; k < 8; ++k) {
    int P = pbase + k * 256 + tid;
    if (P < NPAIR) {
      int t0 = 2 * P;
      const float* p; int l0, LN;
      if (t0 < 92416)       { p = p2; l0 = t0;          LN = 92416; }
      else if (t0 < 115520) { p = p3; l0 = t0 - 92416;  LN = 23104; }
      else if (t0 < 121296) { p = p4; l0 = t0 - 115520; LN = 5776;  }
      else                  { p = p5; l0 = t0 - 121296; LN = 1444;  }
      // l0 even & LN even -> both float4 loads 16B-aligned
      const float* q = p + ((size_t)b * LN + (size_t)l0) * 6 + 4;
      float4 v1 = *(const float4*)(q);      // conf0, cls0, t0_1, t1_1
      float4 v2 = *(const float4*)(q + 4);  // t2_1, t3_1, conf1, cls1
      float s0 = sigm(v1.x) * sigm(v1.y);
      float s1 = sigm(v2.z) * sigm(v2.w);
      u32 b0 = (s0 >= SCORE_T) ? __float_as_uint(s0) : 0u;
      u32 b1 = (s1 >= SCORE_T) ? __float_as_uint(s1) : 0u;
      srow[P] = make_uint2(b0, b1);
      if (b0) atomicAdd(&lhist[score_bin(b0)], 1u);
      if (b1) atomicAdd(&lhist[score_bin(b1)], 1u);
    }
  }
  __syncthreads();
  u32* gh = hist + (size_t)b * NBIN;
  for (int i = tid; i < NBIN; i += 256) {
    u32 v = lhist[i];
    if (v) atomicAdd(&gh[i], v);
  }
}

// ---------------------------------------------------------------- B1: cutoff + filter
// 15 blocks/batch; each recomputes cutoff B from global hist (cheap), scans its
// 8192-proposal slice, appends survivors (deterministic set, <=KTOP/batch) via
// LDS staging + ONE global atomic per block.
__global__ __launch_bounds__(256)
void filter_kernel(const u32* __restrict__ scores, const u32* __restrict__ hist,
                   u32* __restrict__ counters, uint2* __restrict__ compact)
{
  __shared__ u32 shist[NBIN];
  __shared__ u32 scan[256];
  __shared__ uint2 cand[KTOP];
  __shared__ u32 s_cnt, s_base;
  __shared__ int s_B;
  const int tid = threadIdx.x;
  const int b = blockIdx.y;

  const u32* gh = hist + (size_t)b * NBIN;
  for (int i = tid; i < NBIN; i += 256) shist[i] = gh[i];
  if (tid == 0) s_cnt = 0u;
  __syncthreads();

  // suffix counts: scan[t] = cnt_ge(16t)
  u32 g = 0;
  const int base = tid * 16;
  #pragma unroll
  for (int k = 0; k < 16; ++k) g += shist[base + k];
  scan[tid] = g;
  __syncthreads();
  for (int off = 1; off < 256; off <<= 1) {
    u32 v = (tid + off < 256) ? scan[tid + off] : 0u;
    __syncthreads();
    scan[tid] += v;
    __syncthreads();
  }
  // cutoff B = min{ bin : cnt_ge(bin) <= KTOP }  (deterministic keep-set)
  if (tid == 0 && scan[0] <= (u32)KTOP) s_B = 1;
  {
    u32 nxt = (tid < 255) ? scan[tid + 1] : 0u;
    if (scan[tid] > (u32)KTOP && nxt <= (u32)KTOP) {
      u32 c = nxt;
      int Bv = base + 16;
      for (int bin = base + 15; bin >= base; --bin) {
        c += shist[bin];
        if (c <= (u32)KTOP) Bv = bin; else break;
      }
      s_B = Bv;
    }
  }
  __syncthreads();
  const int B = max(s_B, 1);

  // scan slice (coalesced uint4), stage survivors in LDS
  const uint4* sp = (const uint4*)(scores + (size_t)b * NTOT);
  const int i0 = blockIdx.x * 2048;
  const int i1 = min(i0 + 2048, NQ);
  for (int i = i0 + tid; i < i1; i += 256) {
    uint4 v = sp[i];
    u32 c4[4] = { v.x, v.y, v.z, v.w };
    #pragma unroll
    for (int c = 0; c < 4; ++c) {
      u32 bits = c4[c];
      if (bits && score_bin(bits) >= B) {
        u32 pos = atomicAdd(&s_cnt, 1u);
        if (pos < (u32)KTOP) cand[pos] = make_uint2(bits, (u32)(4 * i + c));
      }
    }
  }
  __syncthreads();
  const u32 m = min(s_cnt, (u32)KTOP);
  if (tid == 0) s_base = m ? atomicAdd(&counters[(size_t)b * CSTRIDE], m) : 0u;
  __syncthreads();
  const u32 gbase = s_base;
  uint2* crow = compact + (size_t)b * KTOP;
  for (u32 i = tid; i < m; i += 256) {
    u32 dst = gbase + i;
    if (dst < (u32)KTOP) crow[dst] = cand[i];
  }
}

// ---------------------------------------------------------------- B2: sort + NMS
__global__ __launch_bounds__(1024, 1)
void sort_nms_kernel(const uint2* __restrict__ compact, const u32* __restrict__ counters,
                     const float* __restrict__ p2, const float* __restrict__ p3,
                     const float* __restrict__ p4, const float* __restrict__ p5,
                     float* __restrict__ out)
{
  const int b = blockIdx.x;
  const int tid = threadIdx.x;

  __shared__ u64 skey[KTOP];        // 8 KB
  __shared__ float4 sbox[WIN];      // 4 KB
  __shared__ u64 smat[WIN * 4];     // 8 KB IoU>0.5 bitmask matrix
  __shared__ float4 selbox[100];    // 1.6 KB
  __shared__ int s_misc[4];         // [2]=n_sel, [3]=need slow

  const int n = min((int)counters[(size_t)b * CSTRIDE], KTOP);
  const uint2* crow = compact + (size_t)b * KTOP;

  // key in register: score desc, idx asc; sentinel sorts last (ascending sort)
  u64 v;
  if (tid < n) {
    uint2 pr = crow[tid];
    v = ~(((u64)pr.x << 32) | (u32)(~pr.y));
  } else {
    v = ~0ull;
  }

  // hybrid bitonic sort, 1 elem/thread:
  //   jj < 64  -> partner in same wave -> shfl_xor, NO barrier, NO LDS (45 phases)
  //   jj >= 64 -> LDS exchange with 2 barriers (10 phases)
  for (int kk = 2; kk <= KTOP; kk <<= 1) {
    for (int jj = kk >> 1; jj > 0; jj >>= 1) {
      u64 w;
      if (jj >= 64) {
        skey[tid] = v;
        __syncthreads();
        w = skey[tid ^ jj];
        __syncthreads();
      } else {
        w = shfl_xor_u64(v, jj);
      }
      // keep min iff (ascending block) == (this thread is the lower partner)
      bool keep_min = (((tid & kk) == 0) == ((tid & jj) == 0));
      u64 mn = (v < w) ? v : w;
      u64 mx = (v < w) ? w : v;
      v = keep_min ? mn : mx;
    }
  }
  skey[tid] = v;
  __syncthreads();

  const int Wn = min(n, WIN);

  // decode boxes for the window
  if (tid < WIN) {
    sbox[tid] = (tid < Wn) ? decode_box_from_gidx(~(u32)(~skey[tid]), b, p2, p3, p4, p5)
                           : make_float4(0.f, 0.f, 0.f, 0.f);
  }
  __syncthreads();

  // IoU bitmask matrix: bit j of row i = iou(box_i, box_j) > 0.5
  {
    int row = tid >> 2, word = tid & 3;
    u64 bits = 0;
    if (row < Wn) {
      float4 A = sbox[row];
      int j0 = word * 64;
      int je = min(64, Wn - j0);
      for (int j = 0; j < je; ++j)
        if (iou_gt(A, sbox[j0 + j])) bits |= (1ull << j);
    }
    smat[tid] = bits;
  }
  __syncthreads();

  // greedy selection = live-bit scan over sorted order (== argmax-NMS).
  // live[] monotonically loses bits; next candidate found via ffs (suppressed
  // entries cost nothing).
  if (tid == 0) {
    u64 live[4];
    #pragma unroll
    for (int w2 = 0; w2 < 4; ++w2) {
      int lo = w2 * 64;
      live[w2] = (Wn >= lo + 64) ? ~0ull : (Wn > lo ? ((1ull << (Wn - lo)) - 1ull) : 0ull);
    }
    int sel = 0;
    #pragma unroll 1
    for (int w2 = 0; w2 < 4; ++w2) {
      while (live[w2] && sel < 100) {
        int j = (int)__ffsll((unsigned long long)live[w2]) - 1;
        int p = (w2 << 6) + j;
        u64 r0 = smat[p * 4 + 0];
        u64 r1 = smat[p * 4 + 1];
        u64 r2 = smat[p * 4 + 2];
        u64 r3 = smat[p * 4 + 3];
        float4 box = sbox[p];
        u64 kcomp = ~skey[p];
        float sc = __uint_as_float((u32)(kcomp >> 32));
        selbox[sel] = box;
        float* orow = out + (size_t)b * 500 + (size_t)sel * 5;
        orow[0] = box.x; orow[1] = box.y; orow[2] = box.z; orow[3] = box.w; orow[4] = sc;
        sel++;
        live[0] &= ~r0; live[1] &= ~r1; live[2] &= ~r2; live[3] &= ~r3;
        live[w2] &= ~(1ull << j);   // self-bit (defensive; IoU(self)=1 sets it anyway)
      }
    }
    s_misc[2] = sel;
    s_misc[3] = (sel < 100 && n > WIN) ? 1 : 0;
  }
  __syncthreads();

  // exact slow path beyond the window (statistically never taken)
  if (s_misc[3]) {
    if (tid < 64) {
      const int lane = tid;
      int sel = s_misc[2];
      for (int p = WIN; p < n && sel < 100; ++p) {
        u64 kcomp = ~skey[p];
        float4 box = decode_box_from_gidx(~(u32)kcomp, b, p2, p3, p4, p5);
        bool hit = false;
        if (lane < sel) hit = iou_gt(selbox[lane], box);
        if (lane + 64 < sel) hit = hit || iou_gt(selbox[lane + 64], box);
        u64 anyhit = __ballot(hit);
        if (anyhit == 0ull) {
          if (lane == 0) {
            selbox[sel] = box;
            float sc = __uint_as_float((u32)(kcomp >> 32));
            float* orow = out + (size_t)b * 500 + (size_t)sel * 5;
            orow[0] = box.x; orow[1] = box.y; orow[2] = box.z; orow[3] = box.w; orow[4] = sc;
          }
          sel++;
        }
      }
      if (lane == 0) s_misc[2] = sel;
    }
  }
  __syncthreads();

  // zero-fill remaining rows
  const int nsel = s_misc[2];
  for (int i = tid; i < (100 - nsel) * 5; i += 1024)
    out[(size_t)b * 500 + (size_t)nsel * 5 + i] = 0.0f;
}

// ---------------------------------------------------------------- launch
extern "C" void kernel_launch(void* const* d_in, const int* in_sizes, int n_in,
                              void* d_out, int out_size, void* d_ws, size_t ws_size,
                              hipStream_t stream) {
  const float* p2 = (const float*)d_in[0];
  const float* p3 = (const float*)d_in[1];
  const float* p4 = (const float*)d_in[2];
  const float* p5 = (const float*)d_in[3];
  float* out = (float*)d_out;

  unsigned char* w = (unsigned char*)d_ws;
  u32*   hist     = (u32*)w;
  u32*   counters = (u32*)(w + WS_COUNTERS);
  uint2* compact  = (uint2*)(w + WS_COMPACT);
  u32*   scores   = (u32*)(w + WS_SCORES);

  zero_kernel<<<130, 1024, 0, stream>>>(hist);
  decode_score_hist<<<dim3(30, 32), 256, 0, stream>>>(p2, p3, p4, p5, scores, hist);
  filter_kernel<<<dim3(15, 32), 256, 0, stream>>>(scores, hist, counters, compact);
  sort_nms_kernel<<<32, 1024, 0, stream>>>(compact, counters, p2, p3, p4, p5, out);
}